// Round 8
// baseline (157.488 us; speedup 1.0000x reference)
//
#include <hip/hip_runtime.h>
#include <math.h>

#define T_ 30
#define C_ 512
#define N_ 784      // 28*28 = 49 tiles of 16
#define NT_ 49      // n16-tiles per t
#define NA_ 832     // aT n-pitch
#define EPSV 1e-12f

typedef __attribute__((ext_vector_type(8))) short bf16x8;
typedef __attribute__((ext_vector_type(4))) float f32x4;

__device__ __forceinline__ unsigned short f2bf(float f) {
    union { float f; unsigned int u; } v; v.f = f;
    unsigned int r = (v.u + 0x7FFFu + ((v.u >> 16) & 1u)) >> 16;  // RNE
    return (unsigned short)r;
}
__device__ __forceinline__ float bf2f(unsigned short h) {
    union { unsigned int u; float f; } v; v.u = ((unsigned int)h) << 16;
    return v.f;
}

// wh/wl: split-precision bf16 of w, layout [k][c]
__global__ void k_prep(const float* __restrict__ w, unsigned short* __restrict__ wh,
                       unsigned short* __restrict__ wl) {
    int idx = blockIdx.x * 256 + threadIdx.x;  // 0..32767
    float v = w[idx];
    unsigned short h = f2bf(v);
    wh[idx] = h;
    wl[idx] = f2bf(v - bf2f(h));
}

// Transpose x into MFMA-B-fragment-linear layout + sumsq.
// xsh/xsl[t][nt:49][ks:16][lane:64][8]  (ushorts; lane L: n = nt*16+(L&15),
//   c = ks*32+(L>>4)*8 .. +8).  grid (13 n64, 8 c64, 30 t), 256 thr.
__global__ __launch_bounds__(256) void k_trans(
    const float* __restrict__ x, unsigned short* __restrict__ xsh,
    unsigned short* __restrict__ xsl, float* __restrict__ sumsq)
{
    __shared__ float sx[64][65];     // [c-local][n-local]
    __shared__ float wred[4][64];
    int n0 = blockIdx.x * 64, c0 = blockIdx.y * 64, t = blockIdx.z;
    int tid = threadIdx.x;
    int cr = tid >> 4, li = tid & 15;
    int w = tid >> 6;
    float ss[4] = {0.f, 0.f, 0.f, 0.f};

    #pragma unroll
    for (int j = 0; j < 4; ++j) {
        int cl = j * 16 + cr;
        int n = n0 + li * 4;
        float4 q = make_float4(0.f, 0.f, 0.f, 0.f);
        if (n < N_)  // N_ multiple of 4
            q = *reinterpret_cast<const float4*>(x + ((size_t)t * C_ + c0 + cl) * N_ + n);
        ss[0] = fmaf(q.x, q.x, ss[0]); ss[1] = fmaf(q.y, q.y, ss[1]);
        ss[2] = fmaf(q.z, q.z, ss[2]); ss[3] = fmaf(q.w, q.w, ss[3]);
        sx[cl][li * 4 + 0] = q.x; sx[cl][li * 4 + 1] = q.y;
        sx[cl][li * 4 + 2] = q.z; sx[cl][li * 4 + 3] = q.w;
    }
    #pragma unroll
    for (int i = 0; i < 4; ++i) {
        ss[i] += __shfl_xor(ss[i], 16, 64);
        ss[i] += __shfl_xor(ss[i], 32, 64);
    }
    if (((tid >> 4) & 3) == 0) {
        wred[w][li * 4 + 0] = ss[0]; wred[w][li * 4 + 1] = ss[1];
        wred[w][li * 4 + 2] = ss[2]; wred[w][li * 4 + 3] = ss[3];
    }
    __syncthreads();
    if (tid < 64 && n0 + tid < N_) {
        float s = wred[0][tid] + wred[1][tid] + wred[2][tid] + wred[3][tid];
        atomicAdd(&sumsq[t * N_ + n0 + tid], s);
    }

    // swizzled writes: 8 chunks (4 nsub x 2 ksl), 32 threads/chunk, 2 lanes/thread
    int chunk = tid >> 5;            // 0..7
    int nsub = chunk & 3, ksl = chunk >> 2;
    int ln0 = tid & 31;
    if (n0 + nsub * 16 < N_) {       // nt < 49 (49*16 = 784 exactly)
        int nt = (n0 >> 4) + nsub;
        int ks = (c0 >> 5) + ksl;
        size_t base = (((size_t)t * NT_ + nt) * 16 + ks) * 512;  // ushorts
        #pragma unroll
        for (int h = 0; h < 2; ++h) {
            int L = ln0 + h * 32;
            int nl = nsub * 16 + (L & 15);
            int cl = ksl * 32 + (L >> 4) * 8;
            unsigned int hiw[4], low[4];
            #pragma unroll
            for (int e = 0; e < 4; ++e) {
                union { float f; unsigned int u; } a0, a1, h0, h1;
                a0.f = sx[cl + 2 * e][nl];
                a1.f = sx[cl + 2 * e + 1][nl];
                h0.u = a0.u & 0xFFFF0000u;
                h1.u = a1.u & 0xFFFF0000u;
                hiw[e] = (a0.u >> 16) | h1.u;
                unsigned int l0 = f2bf(a0.f - h0.f);
                unsigned int l1 = f2bf(a1.f - h1.f);
                low[e] = l0 | (l1 << 16);
            }
            *reinterpret_cast<uint4*>(xsh + base + (size_t)L * 8) =
                make_uint4(hiw[0], hiw[1], hiw[2], hiw[3]);
            *reinterpret_cast<uint4*>(xsl + base + (size_t)L * 8) =
                make_uint4(low[0], low[1], low[2], low[3]);
        }
    }
}

// logits (3-product split-bf16 MFMA, B = linear xswz stream) + softmax + aT + asum.
// grid (49, 30), 256 thr. Block: 16 n x 64 k; c split over 4 waves (128 each).
__global__ __launch_bounds__(256) void k_assign(
    const unsigned short* __restrict__ xsh, const unsigned short* __restrict__ xsl,
    const unsigned short* __restrict__ wh, const unsigned short* __restrict__ wl,
    const float* __restrict__ b, const float* __restrict__ sumsq,
    unsigned short* __restrict__ aT, float* __restrict__ asum)
{
    __shared__ float red[4 * 16 * 68];   // [w][n][k] partials
    int t = blockIdx.y, nt = blockIdx.x;
    int tid = threadIdx.x;
    int w = tid >> 6, L = tid & 63, lid = L & 15, quad = L >> 4;

    f32x4 acc[4];
    #pragma unroll
    for (int mt = 0; mt < 4; ++mt)
        #pragma unroll
        for (int r = 0; r < 4; ++r) acc[mt][r] = 0.f;

    const unsigned short* bhb = xsh + (((size_t)t * NT_ + nt) * 16) * 512 + (size_t)L * 8;
    const unsigned short* blb = xsl + (((size_t)t * NT_ + nt) * 16) * 512 + (size_t)L * 8;

    #pragma unroll
    for (int j = 0; j < 4; ++j) {
        int ks = w * 4 + j;
        bf16x8 bh = *reinterpret_cast<const bf16x8*>(bhb + (size_t)ks * 512);
        bf16x8 bl = *reinterpret_cast<const bf16x8*>(blb + (size_t)ks * 512);
        int cs = ks * 32 + quad * 8;
        #pragma unroll
        for (int mt = 0; mt < 4; ++mt) {
            bf16x8 ah = *reinterpret_cast<const bf16x8*>(wh + (size_t)(mt * 16 + lid) * C_ + cs);
            bf16x8 al = *reinterpret_cast<const bf16x8*>(wl + (size_t)(mt * 16 + lid) * C_ + cs);
            acc[mt] = __builtin_amdgcn_mfma_f32_16x16x32_bf16(ah, bh, acc[mt], 0, 0, 0);
            acc[mt] = __builtin_amdgcn_mfma_f32_16x16x32_bf16(al, bh, acc[mt], 0, 0, 0);
            acc[mt] = __builtin_amdgcn_mfma_f32_16x16x32_bf16(ah, bl, acc[mt], 0, 0, 0);
        }
    }
    {
        float* rp = red + w * 1088;
        #pragma unroll
        for (int mt = 0; mt < 4; ++mt)
            *reinterpret_cast<f32x4*>(&rp[lid * 68 + mt * 16 + quad * 4]) = acc[mt];
    }
    __syncthreads();

    // softmax: wave w handles n rows w*4..w*4+3; lane L = k. No n-guards (49*16=784).
    float bk = b[L];
    float asl = 0.f;
    unsigned short av[4];
    #pragma unroll
    for (int i = 0; i < 4; ++i) {
        int n_l = w * 4 + i;
        float v = red[0 * 1088 + n_l * 68 + L] + red[1 * 1088 + n_l * 68 + L]
                + red[2 * 1088 + n_l * 68 + L] + red[3 * 1088 + n_l * 68 + L];
        float s = sumsq[t * N_ + nt * 16 + n_l];      // wave-uniform -> scalar load
        float inv = 1.0f / fmaxf(sqrtf(s), EPSV);
        v = fmaf(v, inv, bk);
        float mx = v;
        #pragma unroll
        for (int m = 1; m <= 32; m <<= 1) mx = fmaxf(mx, __shfl_xor(mx, m, 64));
        float e = __expf(v - mx);
        float se = e;
        #pragma unroll
        for (int m = 1; m <= 32; m <<= 1) se += __shfl_xor(se, m, 64);
        float a = e / se;
        av[i] = f2bf(a * inv);
        asl += a;
    }
    atomicAdd(&asum[t * 64 + L], asl);
    ushort4 st; st.x = av[0]; st.y = av[1]; st.z = av[2]; st.w = av[3];
    *reinterpret_cast<ushort4*>(aT + ((size_t)t * 64 + L) * NA_ + nt * 16 + w * 4) = st;
}

// vlad[t][k][c] = sum_n ahat[k][n]*x[c][n] - asum[k]*cent[k][c]; g2[t][k] = sum_c v^2.
// grid (32, 30), 256 thr. Block: 16 c x 64 k; n split over 4 waves. x re-read is L3-hot.
__global__ __launch_bounds__(256) void k_vlad(
    const float* __restrict__ x, const unsigned short* __restrict__ aT,
    const float* __restrict__ asum, const float* __restrict__ cent,
    float* __restrict__ vlad, float* __restrict__ g2)
{
    __shared__ float red[4][16 * 68];
    int t = blockIdx.y, c0 = blockIdx.x * 16;
    int tid = threadIdx.x;
    int w = tid >> 6, L = tid & 63, lid = L & 15, quad = L >> 4;

    f32x4 acc[4];
    #pragma unroll
    for (int mt = 0; mt < 4; ++mt)
        #pragma unroll
        for (int r = 0; r < 4; ++r) acc[mt][r] = 0.f;

    const float* xrow = x + ((size_t)t * C_ + c0 + lid) * N_;
    const unsigned short* ab = aT + (size_t)t * 64 * NA_;

    for (int s = w; s < 25; s += 4) {
        int nb = s * 32 + quad * 8;
        int nbc = nb > 776 ? 776 : nb;   // clamped lanes multiply aT zeros (memset)
        float4 x0 = *reinterpret_cast<const float4*>(xrow + nbc);
        float4 x1 = *reinterpret_cast<const float4*>(xrow + nbc + 4);
        bf16x8 bb;
        bb[0] = (short)f2bf(x0.x); bb[1] = (short)f2bf(x0.y);
        bb[2] = (short)f2bf(x0.z); bb[3] = (short)f2bf(x0.w);
        bb[4] = (short)f2bf(x1.x); bb[5] = (short)f2bf(x1.y);
        bb[6] = (short)f2bf(x1.z); bb[7] = (short)f2bf(x1.w);
        #pragma unroll
        for (int mt = 0; mt < 4; ++mt) {
            bf16x8 af = *reinterpret_cast<const bf16x8*>(ab + (size_t)(mt * 16 + lid) * NA_ + nb);
            acc[mt] = __builtin_amdgcn_mfma_f32_16x16x32_bf16(af, bb, acc[mt], 0, 0, 0);
        }
    }
    {
        float* rp = &red[w][0];
        #pragma unroll
        for (int mt = 0; mt < 4; ++mt)
            *reinterpret_cast<f32x4*>(&rp[lid * 68 + mt * 16 + quad * 4]) = acc[mt];
    }
    __syncthreads();

    int k = tid >> 2, cs4 = (tid & 3) * 4;
    float as = asum[t * 64 + k];
    float4 cv = *reinterpret_cast<const float4*>(cent + k * C_ + c0 + cs4);
    float4 vout;
    float s2 = 0.f;
    #pragma unroll
    for (int j = 0; j < 4; ++j) {
        int cc = cs4 + j;
        float v = red[0][cc * 68 + k] + red[1][cc * 68 + k]
                + red[2][cc * 68 + k] + red[3][cc * 68 + k];
        v -= as * ((const float*)&cv)[j];
        ((float*)&vout)[j] = v;
        s2 = fmaf(v, v, s2);
    }
    *reinterpret_cast<float4*>(vlad + ((size_t)t * 64 + k) * C_ + c0 + cs4) = vout;
    s2 += __shfl_xor(s2, 1, 64);
    s2 += __shfl_xor(s2, 2, 64);
    if ((tid & 3) == 0) atomicAdd(&g2[t * 64 + k], s2);
}

// out[k*512+c] = sum_t vlad * inv_intra * inv_g  (norm factors from g2)
__global__ __launch_bounds__(256) void k_out(
    const float* __restrict__ vlad, const float* __restrict__ g2,
    float* __restrict__ out)
{
    __shared__ float intr[1920];
    __shared__ float sinv[T_];
    int tid = threadIdx.x;
    for (int i = tid; i < 1920; i += 256)
        intr[i] = 1.0f / fmaxf(sqrtf(g2[i]), EPSV);
    __syncthreads();
    if (tid < T_) {
        float s = 0.f;
        #pragma unroll 8
        for (int k = 0; k < 64; ++k) {
            float iv = intr[tid * 64 + k];
            s += g2[tid * 64 + k] * iv * iv;
        }
        sinv[tid] = 1.0f / fmaxf(sqrtf(s), EPSV);
    }
    __syncthreads();
    int idx = blockIdx.x * 256 + tid;  // k*512+c
    int k = idx >> 9;
    float s = 0.f;
    #pragma unroll 5
    for (int t = 0; t < T_; ++t)
        s += vlad[(size_t)t * 32768 + idx] * intr[t * 64 + k] * sinv[t];
    out[idx] = s;
}

extern "C" void kernel_launch(void* const* d_in, const int* in_sizes, int n_in,
                              void* d_out, int out_size, void* d_ws, size_t ws_size,
                              hipStream_t stream) {
    const float* x    = (const float*)d_in[0];   // 30*512*784
    const float* cent = (const float*)d_in[1];   // 64*512
    const float* w    = (const float*)d_in[2];   // 64*512
    const float* b    = (const float*)d_in[3];   // 64
    float* out = (float*)d_out;

    char* p = (char*)d_ws;
    unsigned short* wh = (unsigned short*)p;  p += 65536;
    unsigned short* wl = (unsigned short*)p;  p += 65536;
    float* sumsq = (float*)p;                 p += 30 * 784 * 4;               // 94080
    // asum + g2 + aT contiguous -> one memset
    float* asum = (float*)p;                  p += 1920 * 4;
    float* g2   = (float*)p;                  p += 1920 * 4;
    unsigned short* aT = (unsigned short*)p;  p += (size_t)T_ * 64 * NA_ * 2;  // 3,194,880
    unsigned short* xsh = (unsigned short*)p; p += (size_t)T_ * NT_ * 16 * 512 * 2; // 24,084,480
    unsigned short* xsl = (unsigned short*)p; p += (size_t)T_ * NT_ * 16 * 512 * 2; // 24,084,480
    float* vlad = (float*)p;                  p += (size_t)T_ * 64 * C_ * 4;   // 3,932,160
    // total ~= 55.6 MB

    k_prep<<<128, 256, 0, stream>>>(w, wh, wl);
    hipMemsetAsync(sumsq, 0, 30 * 784 * 4, stream);
    hipMemsetAsync(asum, 0, 2 * 1920 * 4 + (size_t)T_ * 64 * NA_ * 2, stream);
    k_trans<<<dim3(13, 8, T_), 256, 0, stream>>>(x, xsh, xsl, sumsq);
    k_assign<<<dim3(NT_, T_), 256, 0, stream>>>(xsh, xsl, wh, wl, b, sumsq, aT, asum);
    k_vlad<<<dim3(32, T_), 256, 0, stream>>>(x, aT, asum, cent, vlad, g2);
    k_out<<<128, 256, 0, stream>>>(vlad, g2, out);
}